// Round 1
// 908.450 us; speedup vs baseline: 1.0364x; 1.0364x over previous
//
#include <hip/hip_runtime.h>
#include <stdint.h>

// WanAttentionBlock forward on gfx950 — round 6.
// New: gemm256 — 256x256 8-wave phase-interleaved GEMM (m201-style template):
// BK=64 dbuf, 4 phases/K-tile (Gray-code quadrants), LDS XOR swizzle (c16^=row&7)
// via pre-swizzled global source, raw s_barrier + counted vmcnt (drain hidden by
// early staging), setprio around MFMA clusters, bijective XCD block swizzle.
// Used for qkv (EP1), w1+gelu (EP3), w2 split-K=4 (EP4) + 4-way fused reduce.
// Shapes: B=1, S=2560, DIM=1536, HEADS=12, HD=128, FFN=8960, L2=512.

typedef unsigned short u16;
typedef __bf16 bf16x8 __attribute__((ext_vector_type(8)));
typedef float f32x4 __attribute__((ext_vector_type(4)));

#define DEV __device__ __forceinline__

DEV u16 f2b(float f) {                    // fp32 -> bf16 RNE
  uint32_t u = __float_as_uint(f);
  u += 0x7fffu + ((u >> 16) & 1u);
  return (u16)(u >> 16);
}

DEV float gelu_tanh(float v) {
  float u = 0.7978845608028654f * (v + 0.044715f * v * v * v);
  return 0.5f * v * (1.0f + tanhf(u));
}

// async 16B global->LDS (wave-uniform LDS base + lane*16)
DEV void gl_lds16(const u16* g, u16* l) {
  __builtin_amdgcn_global_load_lds(
      (const __attribute__((address_space(1))) void*)g,
      (__attribute__((address_space(3))) void*)l, 16, 0, 0);
}

// ---- block reductions (256 threads = 4 waves) ----
DEV float bred_sum(float v, float* scr) {
  #pragma unroll
  for (int o = 32; o; o >>= 1) v += __shfl_down(v, o, 64);
  if ((threadIdx.x & 63) == 0) scr[threadIdx.x >> 6] = v;
  __syncthreads();
  v = scr[0] + scr[1] + scr[2] + scr[3];
  __syncthreads();
  return v;
}
DEV float bred_max(float v, float* scr) {
  #pragma unroll
  for (int o = 32; o; o >>= 1) v = fmaxf(v, __shfl_down(v, o, 64));
  if ((threadIdx.x & 63) == 0) scr[threadIdx.x >> 6] = v;
  __syncthreads();
  v = fmaxf(fmaxf(scr[0], scr[1]), fmaxf(scr[2], scr[3]));
  __syncthreads();
  return v;
}
DEV float bred_min(float v, float* scr) {
  #pragma unroll
  for (int o = 32; o; o >>= 1) v = fminf(v, __shfl_down(v, o, 64));
  if ((threadIdx.x & 63) == 0) scr[threadIdx.x >> 6] = v;
  __syncthreads();
  v = fminf(fminf(scr[0], scr[1]), fminf(scr[2], scr[3]));
  __syncthreads();
  return v;
}

// ---- small prep kernels ----
__global__ __launch_bounds__(256) void pack_kernel(
    const float* __restrict__ e, const float* __restrict__ mod,
    const float* __restrict__ cbk, const float* __restrict__ cbv,
    float* __restrict__ em, float* __restrict__ bckv) {
  int i = blockIdx.x * 256 + threadIdx.x;
  if (i < 9216) em[i] = e[i] + mod[i];
  if (i < 3072) bckv[i] = (i < 1536) ? cbk[i] : cbv[i - 1536];
}

__global__ __launch_bounds__(256) void cvt_bf16_kernel(
    const float* __restrict__ in, u16* __restrict__ out, int n4) {
  int stride = gridDim.x * 256;
  for (int i = blockIdx.x * 256 + threadIdx.x; i < n4; i += stride) {
    float4 v = ((const float4*)in)[i];
    uint2 r;
    r.x = (uint32_t)f2b(v.x) | ((uint32_t)f2b(v.y) << 16);
    r.y = (uint32_t)f2b(v.z) | ((uint32_t)f2b(v.w) << 16);
    ((uint2*)out)[i] = r;
  }
}

// LN + modulation + per-token dynamic int8 quant (stored as exact bf16)
__global__ __launch_bounds__(256) void ln_quant_kernel(
    const float* __restrict__ x, const float* __restrict__ em,
    u16* __restrict__ qx, float* __restrict__ sx, float* __restrict__ sumq) {
  __shared__ float scr[4];
  const int row = blockIdx.x, tid = threadIdx.x;
  const float* xr = x + (size_t)row * 1536;
  float v[6], s = 0.f, s2 = 0.f;
  #pragma unroll
  for (int t = 0; t < 6; t++) { v[t] = xr[tid + t * 256]; s += v[t]; s2 += v[t] * v[t]; }
  s = bred_sum(s, scr); s2 = bred_sum(s2, scr);
  float mean = s / 1536.f;
  float var = s2 / 1536.f - mean * mean;
  float inv = rsqrtf(var + 1e-6f);
  float hv[6], amax = 0.f;
  #pragma unroll
  for (int t = 0; t < 6; t++) {
    int i = tid + t * 256;
    hv[t] = (v[t] - mean) * inv * (1.f + em[1536 + i]) + em[i];
    amax = fmaxf(amax, fabsf(hv[t]));
  }
  amax = bred_max(amax, scr);
  float sxv = fmaxf(amax / 127.f, 1e-8f);
  float qs = 0.f;
  #pragma unroll
  for (int t = 0; t < 6; t++) {
    int i = tid + t * 256;
    float q = fminf(fmaxf(rintf(hv[t] / sxv), -127.f), 127.f);
    qs += q;
    qx[(size_t)row * 1536 + i] = f2b(q);
  }
  qs = bred_sum(qs, scr);
  if (tid == 0) { sx[row] = sxv; sumq[row] = qs; }
}

// per-output-channel asymmetric int8 weight quant for stacked [wq;wk;wv]
__global__ __launch_bounds__(256) void quantw_kernel(
    const float* __restrict__ wq, const float* __restrict__ wk, const float* __restrict__ wv,
    const float* __restrict__ bq, const float* __restrict__ bk, const float* __restrict__ bv,
    u16* __restrict__ qw, float* __restrict__ sw, float* __restrict__ zp, float* __restrict__ ball) {
  __shared__ float scr[4];
  const int row = blockIdx.x, tid = threadIdx.x;
  const int sel = (row >= 3072) ? 2 : (row >= 1536 ? 1 : 0);
  const int r = row - sel * 1536;
  const float* w = sel == 0 ? wq : (sel == 1 ? wk : wv);
  const float* bb = sel == 0 ? bq : (sel == 1 ? bk : bv);
  const float* wr = w + (size_t)r * 1536;
  float v[6], mn = 1e30f, mx = -1e30f;
  #pragma unroll
  for (int t = 0; t < 6; t++) { v[t] = wr[tid + t * 256]; mn = fminf(mn, v[t]); mx = fmaxf(mx, v[t]); }
  mn = bred_min(mn, scr); mx = bred_max(mx, scr);
  float s = fmaxf((mx - mn) / 255.f, 1e-8f);
  float z = rintf(-128.f - mn / s);
  #pragma unroll
  for (int t = 0; t < 6; t++) {
    int i = tid + t * 256;
    float q = fminf(fmaxf(rintf(v[t] / s) + z, -128.f), 127.f);
    qw[(size_t)row * 1536 + i] = f2b(q);
  }
  if (tid == 0) { sw[row] = s; zp[row] = z; ball[row] = bb[r]; }
}

// epilogue helper
template<int EP>
DEV void gemm_epilogue(float v, int row, int col, int N, void* Cout,
                       const float* bias, const float* sxp, const float* sumqp,
                       const float* swp, const float* zpp,
                       const float* gp, const float* residp) {
  size_t idx = (size_t)row * N + col;
  if constexpr (EP == 0) {
    ((float*)Cout)[idx] = v + bias[col];
  } else if constexpr (EP == 1) {
    v = (v - sumqp[row] * zpp[col]) * (sxp[row] * swp[col]) + bias[col];
    ((float*)Cout)[idx] = v;
  } else if constexpr (EP == 2) {
    v += bias[col];
    if (gp) v *= gp[col];
    ((float*)Cout)[idx] = v + residp[idx];
  } else if constexpr (EP == 3) {
    ((u16*)Cout)[idx] = f2b(gelu_tanh(v + bias[col]));
  } else {
    ((float*)Cout)[idx] = v;       // raw partial (split-K)
  }
}

struct PtrQuad { void* p0; void* p1; void* p2; void* p3; };

// ---- 256x256 8-wave phase-interleaved GEMM: C[M,N] = A[M,K] * B[N,K]^T ----
// 8 waves as 2(M)x4(N); per-wave 128x64 output = acc[8][4] f32x4.
// K-tile BK=64, double-buffered (128 KiB LDS). Per tile: 4 phases, each
// {ds_read quadrant frags, (stage next tile early), s_barrier, setprio+16 MFMA,
//  s_barrier}; vmcnt(0) once per tile just before the last barrier (loads were
// issued 2-3 phases earlier -> drain is hidden). LDS swizzle c16 ^= row&7
// applied on the READ side + pre-swizzled global SOURCE on the staging side
// (global_load_lds destination must stay linear).
template<int EP>
__global__ __launch_bounds__(512, 2) void gemm256_bt_kernel(
    const u16* __restrict__ A, const u16* __restrict__ B, PtrQuad pq,
    int N, int K, int KC,
    const float* __restrict__ bias,
    const float* __restrict__ sxp, const float* __restrict__ sumqp,
    const float* __restrict__ swp, const float* __restrict__ zpp) {
  __shared__ __align__(16) u16 As[2][256 * 64];
  __shared__ __align__(16) u16 Bs[2][256 * 64];
  const int tid = threadIdx.x;
  const int wave = tid >> 6, lane = tid & 63;
  const int wm = wave >> 2, wn = wave & 3;
  const int quad = lane >> 4, l16 = lane & 15;

  // bijective XCD swizzle over the full 3D linear block id (m204 formula)
  const int gx = gridDim.x, gy = gridDim.y;
  const int nwg = gx * gy * (int)gridDim.z;
  const int orig = ((int)blockIdx.z * gy + (int)blockIdx.y) * gx + (int)blockIdx.x;
  const int qq = nwg >> 3, rr = nwg & 7, xcd = orig & 7, lin = orig >> 3;
  const int wg = (xcd < rr ? xcd * (qq + 1) : rr * (qq + 1) + (xcd - rr) * qq) + lin;
  const int bx = wg % gx, t2 = wg / gx, by = t2 % gy, bz = t2 / gy;
  const int m0 = by * 256, n0 = bx * 256;

  const u16* Abase = A + (size_t)m0 * K + (size_t)bz * KC;
  const u16* Bbase = B + (size_t)n0 * K + (size_t)bz * KC;

  // staging: 4 loads/thread/operand/tile; load i covers LDS 16B slot i*512+tid.
  // linear dest (row = idx>>3, c16 = idx&7) <- global col16 (c16 ^ (row&7)).
  const u16* ap[4]; const u16* bp[4];
  #pragma unroll
  for (int i = 0; i < 4; i++) {
    int idx = i * 512 + tid;
    int row = idx >> 3;
    int col = ((idx & 7) ^ (row & 7)) * 8;
    ap[i] = Abase + (size_t)row * K + col;
    bp[i] = Bbase + (size_t)row * K + col;
  }

  f32x4 acc[8][4];
  #pragma unroll
  for (int i = 0; i < 8; i++)
    #pragma unroll
    for (int j = 0; j < 4; j++) acc[i][j] = (f32x4){0.f, 0.f, 0.f, 0.f};

  auto stA = [&](int buf, int kt) {
    #pragma unroll
    for (int i = 0; i < 4; i++)
      gl_lds16(ap[i] + (kt << 6), &As[buf][(i * 512 + wave * 64) * 8]);
  };
  auto stB = [&](int buf, int kt) {
    #pragma unroll
    for (int i = 0; i < 4; i++)
      gl_lds16(bp[i] + (kt << 6), &Bs[buf][(i * 512 + wave * 64) * 8]);
  };

  bf16x8 afr[4][2], bfr[2][2];
  auto ldA = [&](int cur, int mh) {
    #pragma unroll
    for (int f = 0; f < 4; f++) {
      int row = wm * 128 + mh * 64 + f * 16 + l16;
      int rx = row & 7;
      #pragma unroll
      for (int kk = 0; kk < 2; kk++)
        afr[f][kk] = *(const bf16x8*)&As[cur][row * 64 + (((kk * 4 + quad) ^ rx) << 3)];
    }
  };
  auto ldB = [&](int cur, int nh) {
    #pragma unroll
    for (int f = 0; f < 2; f++) {
      int row = wn * 64 + nh * 32 + f * 16 + l16;
      int rx = row & 7;
      #pragma unroll
      for (int kk = 0; kk < 2; kk++)
        bfr[f][kk] = *(const bf16x8*)&Bs[cur][row * 64 + (((kk * 4 + quad) ^ rx) << 3)];
    }
  };
  auto mmaQ = [&](int mh, int nh) {
    __builtin_amdgcn_s_setprio(1);
    #pragma unroll
    for (int kk = 0; kk < 2; kk++)
      #pragma unroll
      for (int f = 0; f < 4; f++)
        #pragma unroll
        for (int g = 0; g < 2; g++)
          acc[mh * 4 + f][nh * 2 + g] = __builtin_amdgcn_mfma_f32_16x16x32_bf16(
              afr[f][kk], bfr[g][kk], acc[mh * 4 + f][nh * 2 + g], 0, 0, 0);
    __builtin_amdgcn_s_setprio(0);
  };

  const int nk = KC >> 6;
  // prologue: stage tile 0 into buf 0
  stA(0, 0); stB(0, 0);
  asm volatile("s_waitcnt vmcnt(0)" ::: "memory");
  __builtin_amdgcn_s_barrier();

  for (int kt = 0; kt < nk; kt++) {
    const int cur = kt & 1, nxt = cur ^ 1;
    const bool pf = (kt + 1 < nk);
    // phase 0: quadrant (0,0); stage next-tile A early
    ldA(cur, 0); ldB(cur, 0);
    if (pf) stA(nxt, kt + 1);
    __builtin_amdgcn_s_barrier();
    mmaQ(0, 0);
    __builtin_amdgcn_s_barrier();
    // phase 1: quadrant (0,1); stage next-tile B
    ldB(cur, 1);
    if (pf) stB(nxt, kt + 1);
    __builtin_amdgcn_s_barrier();
    mmaQ(0, 1);
    __builtin_amdgcn_s_barrier();
    // phase 2: quadrant (1,1) (reuses B nh=1 regs)
    ldA(cur, 1);
    __builtin_amdgcn_s_barrier();
    mmaQ(1, 1);
    __builtin_amdgcn_s_barrier();
    // phase 3: quadrant (1,0); end-of-tile wait (hidden under MFMA above)
    ldB(cur, 0);
    __builtin_amdgcn_s_barrier();
    mmaQ(1, 0);
    if (pf) asm volatile("s_waitcnt vmcnt(0)" ::: "memory");
    __builtin_amdgcn_s_barrier();
  }

  void* Cuse;
  if constexpr (EP == 4)
    Cuse = bz == 0 ? pq.p0 : (bz == 1 ? pq.p1 : (bz == 2 ? pq.p2 : pq.p3));
  else
    Cuse = pq.p0;
  #pragma unroll
  for (int mi = 0; mi < 8; mi++)
    #pragma unroll
    for (int ni = 0; ni < 4; ni++) {
      int col = n0 + wn * 64 + ni * 16 + l16;
      #pragma unroll
      for (int r = 0; r < 4; r++)
        gemm_epilogue<EP>(acc[mi][ni][r], m0 + wm * 128 + mi * 16 + quad * 4 + r, col,
                          N, Cuse, bias, sxp, sumqp, swp, zpp, nullptr, nullptr);
    }
}

// ---- 64x128 BK=64 double-buffered GEMM (N=1536 projections) ----
template<int EP>
__global__ __launch_bounds__(256) void gemm64_bt_kernel(
    const u16* __restrict__ A, const u16* __restrict__ B,
    void* __restrict__ Cout, void* __restrict__ Cout2, int N, int K, int KC,
    const float* __restrict__ bias,
    const float* __restrict__ sxp, const float* __restrict__ sumqp,
    const float* __restrict__ swp, const float* __restrict__ zpp,
    const float* __restrict__ gp, const float* __restrict__ residp) {
  __shared__ __align__(16) u16 As[2][64 * 64];
  __shared__ __align__(16) u16 Bs[2][128 * 64];
  const int tid = threadIdx.x;
  const int wave = tid >> 6, lane = tid & 63;
  const int wm = wave >> 1, wn = wave & 1;
  const int quad = lane >> 4, l16 = lane & 15;
  const int m0 = blockIdx.y * 64, n0 = blockIdx.x * 128;
  const int kstart = blockIdx.z * KC;

  int arow[2], acol[2], brow[4], bcol[4];
  #pragma unroll
  for (int i = 0; i < 2; i++) {
    int row = (wave * 2 + i) * 8 + (lane >> 3);
    arow[i] = row; acol[i] = (((lane & 7) - (row >> 1)) & 7) * 8;
  }
  #pragma unroll
  for (int i = 0; i < 4; i++) {
    int row = (wave * 4 + i) * 8 + (lane >> 3);
    brow[i] = row; bcol[i] = (((lane & 7) - (row >> 1)) & 7) * 8;
  }

  f32x4 acc[2][4];
  #pragma unroll
  for (int i = 0; i < 2; i++)
    #pragma unroll
    for (int j = 0; j < 4; j++) acc[i][j] = (f32x4){0.f, 0.f, 0.f, 0.f};

  const int nk = KC >> 6;
  auto stage = [&](int buf, int k0) {
    #pragma unroll
    for (int i = 0; i < 2; i++)
      gl_lds16(A + (size_t)(m0 + arow[i]) * K + kstart + k0 + acol[i],
               &As[buf][(wave * 2 + i) * 512]);
    #pragma unroll
    for (int i = 0; i < 4; i++)
      gl_lds16(B + (size_t)(n0 + brow[i]) * K + kstart + k0 + bcol[i],
               &Bs[buf][(wave * 4 + i) * 512]);
  };
  stage(0, 0);
  for (int kt = 0; kt < nk; kt++) {
    __syncthreads();
    const int cur = kt & 1;
    if (kt + 1 < nk) stage(1 - cur, (kt + 1) << 6);
    #pragma unroll
    for (int s = 0; s < 2; s++) {
      bf16x8 af[2], bfv[4];
      #pragma unroll
      for (int mi = 0; mi < 2; mi++) {
        int row = wm * 32 + mi * 16 + l16;
        int slot = ((s * 4 + quad) + (row >> 1)) & 7;
        af[mi] = *(const bf16x8*)&As[cur][row * 64 + slot * 8];
      }
      #pragma unroll
      for (int ni = 0; ni < 4; ni++) {
        int row = wn * 64 + ni * 16 + l16;
        int slot = ((s * 4 + quad) + (row >> 1)) & 7;
        bfv[ni] = *(const bf16x8*)&Bs[cur][row * 64 + slot * 8];
      }
      #pragma unroll
      for (int mi = 0; mi < 2; mi++)
        #pragma unroll
        for (int ni = 0; ni < 4; ni++)
          acc[mi][ni] = __builtin_amdgcn_mfma_f32_16x16x32_bf16(af[mi], bfv[ni], acc[mi][ni], 0, 0, 0);
    }
  }
  void* Cuse = (EP == 4 && blockIdx.z) ? Cout2 : Cout;
  #pragma unroll
  for (int mi = 0; mi < 2; mi++)
    #pragma unroll
    for (int ni = 0; ni < 4; ni++) {
      int col = n0 + wn * 64 + ni * 16 + l16;
      #pragma unroll
      for (int r = 0; r < 4; r++)
        gemm_epilogue<EP>(acc[mi][ni][r], m0 + wm * 32 + mi * 16 + quad * 4 + r, col,
                          N, Cuse, bias, sxp, sumqp, swp, zpp, gp, residp);
    }
}

// split-K tail: out = (P0+P1+P2+P3+bias)*g + resid (fp32)
__global__ __launch_bounds__(256) void splitk_reduce4_kernel(
    const float* __restrict__ P0, const float* __restrict__ P1,
    const float* __restrict__ P2, const float* __restrict__ P3,
    float* __restrict__ out, const float* __restrict__ bias,
    const float* __restrict__ g, const float* __restrict__ resid,
    int N, int n4) {
  int stride = gridDim.x * 256;
  for (int i = blockIdx.x * 256 + threadIdx.x; i < n4; i += stride) {
    float4 a = ((const float4*)P0)[i];
    float4 b = ((const float4*)P1)[i];
    float4 c = ((const float4*)P2)[i];
    float4 d = ((const float4*)P3)[i];
    float4 r = ((const float4*)resid)[i];
    int col = (i * 4) % N;
    float4 o;
    o.x = (a.x + b.x + c.x + d.x + bias[col]) * g[col] + r.x;
    o.y = (a.y + b.y + c.y + d.y + bias[col + 1]) * g[col + 1] + r.y;
    o.z = (a.z + b.z + c.z + d.z + bias[col + 2]) * g[col + 2] + r.z;
    o.w = (a.w + b.w + c.w + d.w + bias[col + 3]) * g[col + 3] + r.w;
    ((float4*)out)[i] = o;
  }
}

// RMS+gate+RoPE for q,k sections + plain convert for v; fp32 qkv -> bf16 qkvb.
__global__ __launch_bounds__(256) void rmsrope_b_kernel(
    const float* __restrict__ qkv, u16* __restrict__ qkvb,
    const float* __restrict__ gq, const float* __restrict__ gk,
    const float* __restrict__ freqs, const int* __restrict__ gsz) {
  __shared__ float scr[4];
  const int row = blockIdx.x, tid = threadIdx.x;
  const float* base = qkv + (size_t)row * 4608;
  u16* ob = qkvb + (size_t)row * 4608;
  const int gh = gsz[1], gw = gsz[2];
  const int hw = gh * gw;
  const int fi = row / hw, rem = row - fi * hw;
  const int hi = rem / gw, wi = rem - hi * gw;
  #pragma unroll
  for (int part = 0; part < 2; part++) {
    const float* p = base + part * 1536;
    u16* o = ob + part * 1536;
    const float* g = part ? gk : gq;
    const float sc = part ? 1.f : 0.08838834764831845f;
    float v[6], s2 = 0.f;
    #pragma unroll
    for (int t = 0; t < 6; t++) { v[t] = p[tid + t * 256]; s2 += v[t] * v[t]; }
    s2 = bred_sum(s2, scr);
    float inv = rsqrtf(s2 / 1536.f + 1e-6f);
    #pragma unroll
    for (int t = 0; t < 3; t++) {
      int pr = tid + t * 256;
      int c = pr & 63;
      int frow = (c < 22) ? fi : (c < 43 ? hi : wi);
      const float* fr = freqs + ((size_t)frow * 64 + c) * 2;
      float cv = fr[0], sv = fr[1];
      float x0 = p[2 * pr] * inv * g[2 * pr];
      float x1 = p[2 * pr + 1] * inv * g[2 * pr + 1];
      o[2 * pr] = f2b((x0 * cv - x1 * sv) * sc);
      o[2 * pr + 1] = f2b((x0 * sv + x1 * cv) * sc);
    }
  }
  #pragma unroll
  for (int t = 0; t < 6; t++) {
    int i = tid + t * 256;
    ob[3072 + i] = f2b(base[3072 + i]);
  }
}

// RMS (optional) + scale, fp32 -> bf16
__global__ __launch_bounds__(256) void rms_bf16_kernel(
    const float* __restrict__ X, u16* __restrict__ O, const float* __restrict__ g,
    int ldi, int ldo, float scale) {
  __shared__ float scr[4];
  const int row = blockIdx.x, tid = threadIdx.x;
  const float* xr = X + (size_t)row * ldi;
  u16* orow = O + (size_t)row * ldo;
  float v[6], s2 = 0.f;
  #pragma unroll
  for (int t = 0; t < 6; t++) { v[t] = xr[tid + t * 256]; s2 += v[t] * v[t]; }
  s2 = bred_sum(s2, scr);
  float inv = rsqrtf(s2 / 1536.f + 1e-6f) * scale;
  #pragma unroll
  for (int t = 0; t < 6; t++) {
    int i = tid + t * 256;
    orow[i] = f2b(v[t] * inv * g[i]);
  }
}

// V transpose: fp32 V[kv][ld] (per-head 128 cols) -> bf16 Vt[head][hd][Skv]
__global__ __launch_bounds__(256) void vtrans_kernel(
    const float* __restrict__ V, int ld, u16* __restrict__ Vt, int Skv) {
  __shared__ u16 T[64 * 136];
  const int h = blockIdx.y, k0 = blockIdx.x * 64, tid = threadIdx.x;
  #pragma unroll
  for (int i = 0; i < 8; i++) {
    int f4 = i * 256 + tid;
    int row = f4 >> 5, c4 = f4 & 31;
    float4 v = *(const float4*)(V + (size_t)(k0 + row) * ld + h * 128 + c4 * 4);
    ushort4 b;
    b.x = f2b(v.x); b.y = f2b(v.y); b.z = f2b(v.z); b.w = f2b(v.w);
    *(ushort4*)&T[row * 136 + c4 * 4] = b;
  }
  __syncthreads();
  #pragma unroll
  for (int i = 0; i < 4; i++) {
    int f8 = i * 256 + tid;
    int hd = f8 >> 3, kc = f8 & 7;
    u16 tmp[8];
    #pragma unroll
    for (int j = 0; j < 8; j++) tmp[j] = T[(kc * 8 + j) * 136 + hd];
    *(uint4*)(Vt + ((size_t)h * 128 + hd) * Skv + k0 + kc * 8) = *(const uint4*)tmp;
  }
}

// ---- MFMA flash attention ----
__global__ __launch_bounds__(256) void fattn_kernel(
    const u16* __restrict__ Q, int ldq, const u16* __restrict__ Kg, int ldk,
    const u16* __restrict__ Vtg, u16* __restrict__ O, int ldo,
    const int* __restrict__ klen_ptr, int kmax) {
  __shared__ __align__(16) u16 Qs[64 * 136];
  __shared__ __align__(16) u16 Ks[64 * 136];
  __shared__ __align__(16) u16 Vt[128 * 72];
  __shared__ __align__(16) u16 Pt[4][16 * 72];
  const int tid = threadIdx.x, wave = tid >> 6, lane = tid & 63;
  const int quad = lane >> 4, l16 = lane & 15;
  const int h = blockIdx.y;
  const int q0 = blockIdx.x * 64;
  int klen = klen_ptr[0]; if (klen > kmax) klen = kmax;
  const u16* vbase = Vtg + (size_t)h * 128 * kmax;

  #pragma unroll
  for (int i = 0; i < 4; i++) {
    int c8 = i * 256 + tid;
    int row = c8 >> 4, cc = (c8 & 15) * 8;
    *(uint4*)&Qs[row * 136 + cc] = *(const uint4*)(Q + (size_t)(q0 + row) * ldq + h * 128 + cc);
  }
  __syncthreads();
  bf16x8 qf[4];
  #pragma unroll
  for (int s = 0; s < 4; s++)
    qf[s] = *(const bf16x8*)&Qs[(wave * 16 + l16) * 136 + s * 32 + quad * 8];

  float m_r[4] = {-1e30f, -1e30f, -1e30f, -1e30f};
  float l_r[4] = {0.f, 0.f, 0.f, 0.f};
  f32x4 oacc[8];
  #pragma unroll
  for (int n8 = 0; n8 < 8; n8++) oacc[n8] = (f32x4){0.f, 0.f, 0.f, 0.f};

  const int ktiles = (klen + 63) >> 6;
  for (int kt = 0; kt < ktiles; kt++) {
    const int k0 = kt * 64;
    __syncthreads();
    #pragma unroll
    for (int i = 0; i < 4; i++) {
      int c8 = i * 256 + tid;
      int row = c8 >> 4, cc = (c8 & 15) * 8;
      *(uint4*)&Ks[row * 136 + cc] = *(const uint4*)(Kg + (size_t)(k0 + row) * ldk + h * 128 + cc);
    }
    #pragma unroll
    for (int i = 0; i < 4; i++) {
      int f8 = i * 256 + tid;
      int hd = f8 >> 3, kc = f8 & 7;
      *(uint4*)&Vt[hd * 72 + kc * 8] = *(const uint4*)(vbase + (size_t)hd * kmax + k0 + kc * 8);
    }
    __syncthreads();
    f32x4 sacc[4];
    #pragma unroll
    for (int ni = 0; ni < 4; ni++) sacc[ni] = (f32x4){0.f, 0.f, 0.f, 0.f};
    #pragma unroll
    for (int ni = 0; ni < 4; ni++)
      #pragma unroll
      for (int s = 0; s < 4; s++) {
        bf16x8 kf = *(const bf16x8*)&Ks[(ni * 16 + l16) * 136 + s * 32 + quad * 8];
        sacc[ni] = __builtin_amdgcn_mfma_f32_16x16x32_bf16(qf[s], kf, sacc[ni], 0, 0, 0);
      }
    float alpha_r[4];
    #pragma unroll
    for (int r = 0; r < 4; r++) {
      float mx = -1e30f;
      #pragma unroll
      for (int ni = 0; ni < 4; ni++) {
        int col = k0 + ni * 16 + l16;
        float sv = (col < klen) ? sacc[ni][r] : -1e30f;
        sacc[ni][r] = sv;
        mx = fmaxf(mx, sv);
      }
      #pragma unroll
      for (int off = 1; off < 16; off <<= 1) mx = fmaxf(mx, __shfl_xor(mx, off, 64));
      float mnew = fmaxf(m_r[r], mx);
      float alpha = __expf(m_r[r] - mnew);
      float rsum = 0.f;
      float pv[4];
      #pragma unroll
      for (int ni = 0; ni < 4; ni++) {
        float p = __expf(sacc[ni][r] - mnew);
        pv[ni] = p;
        rsum += p;
      }
      #pragma unroll
      for (int off = 1; off < 16; off <<= 1) rsum += __shfl_xor(rsum, off, 64);
      l_r[r] = l_r[r] * alpha + rsum;
      m_r[r] = mnew;
      alpha_r[r] = alpha;
      #pragma unroll
      for (int ni = 0; ni < 4; ni++)
        Pt[wave][(quad * 4 + r) * 72 + ni * 16 + l16] = f2b(pv[ni]);
    }
    #pragma unroll
    for (int n8 = 0; n8 < 8; n8++)
      #pragma unroll
      for (int r = 0; r < 4; r++) oacc[n8][r] *= alpha_r[r];
    #pragma unroll
    for (int s2 = 0; s2 < 2; s2++) {
      bf16x8 pf = *(const bf16x8*)&Pt[wave][l16 * 72 + s2 * 32 + quad * 8];
      #pragma unroll
      for (int n8 = 0; n8 < 8; n8++) {
        bf16x8 vf = *(const bf16x8*)&Vt[(n8 * 16 + l16) * 72 + s2 * 32 + quad * 8];
        oacc[n8] = __builtin_amdgcn_mfma_f32_16x16x32_bf16(pf, vf, oacc[n8], 0, 0, 0);
      }
    }
  }
  float rl[4];
  #pragma unroll
  for (int r = 0; r < 4; r++) rl[r] = 1.f / l_r[r];
  #pragma unroll
  for (int n8 = 0; n8 < 8; n8++)
    #pragma unroll
    for (int r = 0; r < 4; r++) {
      int row = q0 + wave * 16 + quad * 4 + r;
      O[(size_t)row * ldo + h * 128 + n8 * 16 + l16] = f2b(oacc[n8][r] * rl[r]);
    }
}

// out_bf16 = LN(x) * (addone + w) + b
__global__ __launch_bounds__(256) void ln_affine_kernel(
    const float* __restrict__ X, u16* __restrict__ O,
    const float* __restrict__ w, const float* __restrict__ b, float addone) {
  __shared__ float scr[4];
  const int row = blockIdx.x, tid = threadIdx.x;
  const float* xr = X + (size_t)row * 1536;
  float v[6], s = 0.f, s2 = 0.f;
  #pragma unroll
  for (int t = 0; t < 6; t++) { v[t] = xr[tid + t * 256]; s += v[t]; s2 += v[t] * v[t]; }
  s = bred_sum(s, scr); s2 = bred_sum(s2, scr);
  float mean = s / 1536.f;
  float inv = rsqrtf(s2 / 1536.f - mean * mean + 1e-6f);
  #pragma unroll
  for (int t = 0; t < 6; t++) {
    int i = tid + t * 256;
    O[(size_t)row * 1536 + i] = f2b((v[t] - mean) * inv * (addone + w[i]) + b[i]);
  }
}

extern "C" void kernel_launch(void* const* d_in, const int* in_sizes, int n_in,
                              void* d_out, int out_size, void* d_ws, size_t ws_size,
                              hipStream_t stream) {
  (void)in_sizes; (void)n_in; (void)out_size; (void)ws_size;
  const int S = 2560, D = 1536, L2C = 512, FF = 8960, ND = 4608, CKV = 3072;

  const float* x = (const float*)d_in[0];
  const float* e = (const float*)d_in[1];
  const int* seq_lens = (const int*)d_in[2];
  const int* grid_sz = (const int*)d_in[3];
  const float* freqs = (const float*)d_in[4];
  const float* context = (const float*)d_in[5];
  const int* ctx_lens = (const int*)d_in[6];
  const float* modulation = (const float*)d_in[7];
  const float* wq = (const float*)d_in[8];  const float* bq = (const float*)d_in[9];
  const float* wk = (const float*)d_in[10]; const float* bk = (const float*)d_in[11];
  const float* wv = (const float*)d_in[12]; const float* bv = (const float*)d_in[13];
  const float* wo = (const float*)d_in[14]; const float* bo = (const float*)d_in[15];
  const float* gq = (const float*)d_in[16]; const float* gk = (const float*)d_in[17];
  const float* n3w = (const float*)d_in[18]; const float* n3b = (const float*)d_in[19];
  const float* cwq = (const float*)d_in[20]; const float* cbq = (const float*)d_in[21];
  const float* cwk = (const float*)d_in[22]; const float* cbk = (const float*)d_in[23];
  const float* cwv = (const float*)d_in[24]; const float* cbv = (const float*)d_in[25];
  const float* cwo = (const float*)d_in[26]; const float* cbo = (const float*)d_in[27];
  const float* cgq = (const float*)d_in[28]; const float* cgk = (const float*)d_in[29];
  const float* w1 = (const float*)d_in[30]; const float* b1 = (const float*)d_in[31];
  const float* w2 = (const float*)d_in[32]; const float* b2 = (const float*)d_in[33];

  char* wsb = (char*)d_ws;
  size_t off = 0;
  auto alloc = [&](size_t bytes) -> void* {
    void* r = wsb + off;
    off += (bytes + 255) & ~(size_t)255;
    return r;
  };
  float* em   = (float*)alloc((size_t)6 * D * 4);
  float* bckv = (float*)alloc((size_t)CKV * 4);
  float* ball = (float*)alloc((size_t)ND * 4);
  float* sx   = (float*)alloc((size_t)S * 4);
  float* sumq = (float*)alloc((size_t)S * 4);
  float* sw   = (float*)alloc((size_t)ND * 4);
  float* zp   = (float*)alloc((size_t)ND * 4);
  u16* qx     = (u16*)alloc((size_t)S * D * 2);      // union: cvtg; P0 head
  u16* qw     = (u16*)alloc((size_t)ND * D * 2);     // union: vtg; P0 tail (qx+qw = 22.0MB >= 15.7MB)
  float* qkv  = (float*)alloc((size_t)S * ND * 4);   // union: h3
  u16* qkvb   = (u16*)alloc((size_t)S * ND * 2);     // union: P1 (23.6MB >= 15.7MB)
  u16* attnb  = (u16*)alloc((size_t)S * D * 2);      // union: h2; P2 head
  u16* hx     = (u16*)alloc((size_t)S * D * 2);      // union: cqb; P2 tail (attnb+hx = 15.73MB)
  float* cq   = (float*)alloc((size_t)S * D * 4);    // union: x2
  float* ckv  = (float*)alloc((size_t)L2C * CKV * 4);
  u16* ctxb   = (u16*)alloc((size_t)L2C * D * 2);    // union: ckvb
  u16* cattn  = (u16*)alloc((size_t)S * D * 2);      // P3 head
  u16* wo_b   = (u16*)alloc((size_t)D * D * 2);      // P3 mid
  u16* cwq_b  = (u16*)alloc((size_t)D * D * 2);      // P3 tail (cattn+wo_b+cwq_b = 17.3MB)
  u16* cwkv_b = (u16*)alloc((size_t)2 * D * D * 2);
  u16* cwo_b  = (u16*)alloc((size_t)D * D * 2);
  u16* w1_b   = (u16*)alloc((size_t)FF * D * 2);
  u16* w2_b   = (u16*)alloc((size_t)D * FF * 2);
  u16* h3 = (u16*)qkv;
  u16* h2 = attnb;
  u16* vtg = qw;        // [12][128][2560] bf16
  u16* cvtg = qx;       // [12][128][512] bf16
  u16* cqb = hx;
  u16* ckvb = ctxb;
  float* x2 = cq;
  float* x1 = (float*)d_out;
  float* outp = (float*)d_out;
  // split-K=4 partials (all regions dead during FFN/w2):
  float* P0 = (float*)qx;     // qx+qw region
  float* P1 = (float*)qkvb;   // qkvb region
  float* P2 = (float*)attnb;  // attnb+hx region (contiguous, 15.73MB)
  float* P3 = (float*)cattn;  // cattn+wo_b+cwq_b region (contiguous, 17.3MB)

  auto cvt = [&](const float* in, u16* op, size_t n) {
    int n4 = (int)(n / 4);
    int blocks = (n4 + 255) / 256; if (blocks > 4096) blocks = 4096;
    cvt_bf16_kernel<<<blocks, 256, 0, stream>>>(in, op, n4);
  };

  pack_kernel<<<36, 256, 0, stream>>>(e, modulation, cbk, cbv, em, bckv);
  cvt(wo, wo_b, (size_t)D * D);
  cvt(cwq, cwq_b, (size_t)D * D);
  cvt(cwk, cwkv_b, (size_t)D * D);
  cvt(cwv, cwkv_b + (size_t)D * D, (size_t)D * D);
  cvt(cwo, cwo_b, (size_t)D * D);
  cvt(w1, w1_b, (size_t)FF * D);
  cvt(w2, w2_b, (size_t)D * FF);
  cvt(context, ctxb, (size_t)L2C * D);

  ln_quant_kernel<<<S, 256, 0, stream>>>(x, em, qx, sx, sumq);
  quantw_kernel<<<ND, 256, 0, stream>>>(wq, wk, wv, bq, bk, bv, qw, sw, zp, ball);

  // qkv = dequant(qx @ qw^T) : [S][4608] fp32   (180 blocks @256x256)
  {
    PtrQuad pq{qkv, nullptr, nullptr, nullptr};
    gemm256_bt_kernel<1><<<dim3(ND / 256, S / 256), 512, 0, stream>>>(
        qx, qw, pq, ND, D, D, ball, sx, sumq, sw, zp);
  }

  rmsrope_b_kernel<<<S, 256, 0, stream>>>(qkv, qkvb, gq, gk, freqs, grid_sz);
  vtrans_kernel<<<dim3(S / 64, 12), 256, 0, stream>>>(qkv + 3072, ND, vtg, S);

  fattn_kernel<<<dim3(S / 64, 12), 256, 0, stream>>>(
      qkvb, ND, qkvb + 1536, ND, vtg, attnb, D, seq_lens, S);

  // x1 = x + (attn @ wo^T + bo) * gm
  gemm64_bt_kernel<2><<<dim3(D / 128, S / 64), 256, 0, stream>>>(
      attnb, wo_b, x1, nullptr, D, D, D, bo, nullptr, nullptr, nullptr, nullptr, em + 2 * D, x);

  ln_affine_kernel<<<S, 256, 0, stream>>>(x1, hx, n3w, n3b, 0.f);

  gemm64_bt_kernel<0><<<dim3(D / 128, S / 64), 256, 0, stream>>>(
      hx, cwq_b, cq, nullptr, D, D, D, cbq, nullptr, nullptr, nullptr, nullptr, nullptr, nullptr);
  gemm64_bt_kernel<0><<<dim3(CKV / 128, L2C / 64), 256, 0, stream>>>(
      ctxb, cwkv_b, ckv, nullptr, CKV, D, D, bckv, nullptr, nullptr, nullptr, nullptr, nullptr, nullptr);

  rms_bf16_kernel<<<S, 256, 0, stream>>>(cq, cqb, cgq, D, D, 0.08838834764831845f);
  rms_bf16_kernel<<<L2C, 256, 0, stream>>>(ckv, ckvb, cgk, CKV, D, 1.f);
  vtrans_kernel<<<dim3(L2C / 64, 12), 256, 0, stream>>>(ckv + 1536, CKV, cvtg, L2C);

  fattn_kernel<<<dim3(S / 64, 12), 256, 0, stream>>>(
      cqb, D, ckvb, D, cvtg, cattn, D, ctx_lens, L2C);

  // x2 = x1 + cattn @ cwo^T + cbo
  gemm64_bt_kernel<2><<<dim3(D / 128, S / 64), 256, 0, stream>>>(
      cattn, cwo_b, x2, nullptr, D, D, D, cbo, nullptr, nullptr, nullptr, nullptr, nullptr, x1);

  ln_affine_kernel<<<S, 256, 0, stream>>>(x2, h2, em + 4 * D, em + 3 * D, 1.f);

  // h3 = gelu(h2 @ w1^T + b1) (bf16)   (350 blocks @256x256)
  {
    PtrQuad pq{h3, nullptr, nullptr, nullptr};
    gemm256_bt_kernel<3><<<dim3(FF / 256, S / 256), 512, 0, stream>>>(
        h2, w1_b, pq, FF, D, D, b1, nullptr, nullptr, nullptr, nullptr);
  }

  // w2 split-K=4: raw partials P0..P3 (240 blocks @256x256), then fused reduce
  {
    PtrQuad pq{P0, P1, P2, P3};
    gemm256_bt_kernel<4><<<dim3(D / 256, S / 256, 4), 512, 0, stream>>>(
        h3, w2_b, pq, D, FF, FF / 4, nullptr, nullptr, nullptr, nullptr, nullptr);
  }
  splitk_reduce4_kernel<<<960, 256, 0, stream>>>(
      P0, P1, P2, P3, outp, b2, em + 5 * D, x2, D, S * D / 4);
}

// Round 3
// 881.283 us; speedup vs baseline: 1.0683x; 1.0308x over previous
//
#include <hip/hip_runtime.h>
#include <stdint.h>

// WanAttentionBlock forward on gfx950 — round 8 (round-7 resubmit, hardened).
// gemm256 v2: true counted-vmcnt pipeline. Stage tile kt+2 into buffer `cur`
// AFTER the last reads of `cur` (lgkm0+barrier makes DMA overwrite safe), so
// the end-of-iter wait is vmcnt(8) (tile kt+1 ready, kt+2 in flight) — never
// a drain. gemm64 restructured the same way (2-phase counted vmcnt(6)).
// Hardening vs round 7: sched_barrier(0) after every inline-asm waitcnt
// (rule-18 insurance); gemm64 launch_bounds back to plain 256.
// Shapes: B=1, S=2560, DIM=1536, HEADS=12, HD=128, FFN=8960, L2=512.

typedef unsigned short u16;
typedef __bf16 bf16x8 __attribute__((ext_vector_type(8)));
typedef float f32x4 __attribute__((ext_vector_type(4)));

#define DEV __device__ __forceinline__

#define WAIT_LGKM0 do { \
  asm volatile("s_waitcnt lgkmcnt(0)" ::: "memory"); \
  __builtin_amdgcn_sched_barrier(0); } while (0)
#define WAIT_VM(N) do { \
  asm volatile("s_waitcnt vmcnt(" #N ")" ::: "memory"); \
  __builtin_amdgcn_sched_barrier(0); } while (0)

DEV u16 f2b(float f) {                    // fp32 -> bf16 RNE
  uint32_t u = __float_as_uint(f);
  u += 0x7fffu + ((u >> 16) & 1u);
  return (u16)(u >> 16);
}

DEV float gelu_tanh(float v) {
  // 0.5v(1+tanh(u)) == v * sigmoid(2u); 2*0.7978845608 = 1.5957691216
  float u = 1.5957691216057308f * (v + 0.044715f * v * v * v);
  return v / (1.f + __expf(-u));
}

// async 16B global->LDS (wave-uniform LDS base + lane*16)
DEV void gl_lds16(const u16* g, u16* l) {
  __builtin_amdgcn_global_load_lds(
      (const __attribute__((address_space(1))) void*)g,
      (__attribute__((address_space(3))) void*)l, 16, 0, 0);
}

// ---- block reductions (256 threads = 4 waves) ----
DEV float bred_sum(float v, float* scr) {
  #pragma unroll
  for (int o = 32; o; o >>= 1) v += __shfl_down(v, o, 64);
  if ((threadIdx.x & 63) == 0) scr[threadIdx.x >> 6] = v;
  __syncthreads();
  v = scr[0] + scr[1] + scr[2] + scr[3];
  __syncthreads();
  return v;
}
DEV float bred_max(float v, float* scr) {
  #pragma unroll
  for (int o = 32; o; o >>= 1) v = fmaxf(v, __shfl_down(v, o, 64));
  if ((threadIdx.x & 63) == 0) scr[threadIdx.x >> 6] = v;
  __syncthreads();
  v = fmaxf(fmaxf(scr[0], scr[1]), fmaxf(scr[2], scr[3]));
  __syncthreads();
  return v;
}
DEV float bred_min(float v, float* scr) {
  #pragma unroll
  for (int o = 32; o; o >>= 1) v = fminf(v, __shfl_down(v, o, 64));
  if ((threadIdx.x & 63) == 0) scr[threadIdx.x >> 6] = v;
  __syncthreads();
  v = fminf(fminf(scr[0], scr[1]), fminf(scr[2], scr[3]));
  __syncthreads();
  return v;
}

// ---- small prep kernels ----
__global__ __launch_bounds__(256) void pack_kernel(
    const float* __restrict__ e, const float* __restrict__ mod,
    const float* __restrict__ cbk, const float* __restrict__ cbv,
    float* __restrict__ em, float* __restrict__ bckv) {
  int i = blockIdx.x * 256 + threadIdx.x;
  if (i < 9216) em[i] = e[i] + mod[i];
  if (i < 3072) bckv[i] = (i < 1536) ? cbk[i] : cbv[i - 1536];
}

__global__ __launch_bounds__(256) void cvt_bf16_kernel(
    const float* __restrict__ in, u16* __restrict__ out, int n4) {
  int stride = gridDim.x * 256;
  for (int i = blockIdx.x * 256 + threadIdx.x; i < n4; i += stride) {
    float4 v = ((const float4*)in)[i];
    uint2 r;
    r.x = (uint32_t)f2b(v.x) | ((uint32_t)f2b(v.y) << 16);
    r.y = (uint32_t)f2b(v.z) | ((uint32_t)f2b(v.w) << 16);
    ((uint2*)out)[i] = r;
  }
}

// LN + modulation + per-token dynamic int8 quant (stored as exact bf16)
__global__ __launch_bounds__(256) void ln_quant_kernel(
    const float* __restrict__ x, const float* __restrict__ em,
    u16* __restrict__ qx, float* __restrict__ sx, float* __restrict__ sumq) {
  __shared__ float scr[4];
  const int row = blockIdx.x, tid = threadIdx.x;
  const float* xr = x + (size_t)row * 1536;
  float v[6], s = 0.f, s2 = 0.f;
  #pragma unroll
  for (int t = 0; t < 6; t++) { v[t] = xr[tid + t * 256]; s += v[t]; s2 += v[t] * v[t]; }
  s = bred_sum(s, scr); s2 = bred_sum(s2, scr);
  float mean = s / 1536.f;
  float var = s2 / 1536.f - mean * mean;
  float inv = rsqrtf(var + 1e-6f);
  float hv[6], amax = 0.f;
  #pragma unroll
  for (int t = 0; t < 6; t++) {
    int i = tid + t * 256;
    hv[t] = (v[t] - mean) * inv * (1.f + em[1536 + i]) + em[i];
    amax = fmaxf(amax, fabsf(hv[t]));
  }
  amax = bred_max(amax, scr);
  float sxv = fmaxf(amax / 127.f, 1e-8f);
  float qs = 0.f;
  #pragma unroll
  for (int t = 0; t < 6; t++) {
    int i = tid + t * 256;
    float q = fminf(fmaxf(rintf(hv[t] / sxv), -127.f), 127.f);
    qs += q;
    qx[(size_t)row * 1536 + i] = f2b(q);
  }
  qs = bred_sum(qs, scr);
  if (tid == 0) { sx[row] = sxv; sumq[row] = qs; }
}

// per-output-channel asymmetric int8 weight quant for stacked [wq;wk;wv]
__global__ __launch_bounds__(256) void quantw_kernel(
    const float* __restrict__ wq, const float* __restrict__ wk, const float* __restrict__ wv,
    const float* __restrict__ bq, const float* __restrict__ bk, const float* __restrict__ bv,
    u16* __restrict__ qw, float* __restrict__ sw, float* __restrict__ zp, float* __restrict__ ball) {
  __shared__ float scr[4];
  const int row = blockIdx.x, tid = threadIdx.x;
  const int sel = (row >= 3072) ? 2 : (row >= 1536 ? 1 : 0);
  const int r = row - sel * 1536;
  const float* w = sel == 0 ? wq : (sel == 1 ? wk : wv);
  const float* bb = sel == 0 ? bq : (sel == 1 ? bk : bv);
  const float* wr = w + (size_t)r * 1536;
  float v[6], mn = 1e30f, mx = -1e30f;
  #pragma unroll
  for (int t = 0; t < 6; t++) { v[t] = wr[tid + t * 256]; mn = fminf(mn, v[t]); mx = fmaxf(mx, v[t]); }
  mn = bred_min(mn, scr); mx = bred_max(mx, scr);
  float s = fmaxf((mx - mn) / 255.f, 1e-8f);
  float z = rintf(-128.f - mn / s);
  #pragma unroll
  for (int t = 0; t < 6; t++) {
    int i = tid + t * 256;
    float q = fminf(fmaxf(rintf(v[t] / s) + z, -128.f), 127.f);
    qw[(size_t)row * 1536 + i] = f2b(q);
  }
  if (tid == 0) { sw[row] = s; zp[row] = z; ball[row] = bb[r]; }
}

// epilogue helper
template<int EP>
DEV void gemm_epilogue(float v, int row, int col, int N, void* Cout,
                       const float* bias, const float* sxp, const float* sumqp,
                       const float* swp, const float* zpp,
                       const float* gp, const float* residp) {
  size_t idx = (size_t)row * N + col;
  if constexpr (EP == 0) {
    ((float*)Cout)[idx] = v + bias[col];
  } else if constexpr (EP == 1) {
    v = (v - sumqp[row] * zpp[col]) * (sxp[row] * swp[col]) + bias[col];
    ((float*)Cout)[idx] = v;
  } else if constexpr (EP == 2) {
    v += bias[col];
    if (gp) v *= gp[col];
    ((float*)Cout)[idx] = v + residp[idx];
  } else if constexpr (EP == 3) {
    ((u16*)Cout)[idx] = f2b(gelu_tanh(v + bias[col]));
  } else {
    ((float*)Cout)[idx] = v;       // raw partial (split-K)
  }
}

struct PtrQuad { void* p0; void* p1; void* p2; void* p3; };

// ---- 256x256 8-wave phase-interleaved GEMM: C[M,N] = A[M,K] * B[N,K]^T ----
// 8 waves as 2(M)x4(N); per-wave 128x64 output = acc[8][4] f32x4.
// BK=64, 2 buffers, 2-tiles-deep prefetch. Per tile: 4 phases (Gray-code
// quadrants). Tile kt+2 is staged into buffer `cur` right after the last
// reads of `cur` complete (lgkm0 BEFORE the barrier so all waves' in-flight
// ds_reads are drained before any wave's DMA overwrites). End-of-iter wait:
// vmcnt(8) — tile kt+1 resident, tile kt+2's 8 loads in flight across the
// barrier. LDS swizzle c16 ^= row&7 via pre-swizzled global source.
template<int EP>
__global__ __launch_bounds__(512, 2) void gemm256_bt_kernel(
    const u16* __restrict__ A, const u16* __restrict__ B, PtrQuad pq,
    int N, int K, int KC,
    const float* __restrict__ bias,
    const float* __restrict__ sxp, const float* __restrict__ sumqp,
    const float* __restrict__ swp, const float* __restrict__ zpp) {
  __shared__ __align__(16) u16 As[2][256 * 64];
  __shared__ __align__(16) u16 Bs[2][256 * 64];
  const int tid = threadIdx.x;
  const int wave = tid >> 6, lane = tid & 63;
  const int wm = wave >> 2, wn = wave & 3;
  const int quad = lane >> 4, l16 = lane & 15;

  // bijective XCD swizzle over the full 3D linear block id (m204 formula)
  const int gx = gridDim.x, gy = gridDim.y;
  const int nwg = gx * gy * (int)gridDim.z;
  const int orig = ((int)blockIdx.z * gy + (int)blockIdx.y) * gx + (int)blockIdx.x;
  const int qq = nwg >> 3, rr = nwg & 7, xcd = orig & 7, lin = orig >> 3;
  const int wg = (xcd < rr ? xcd * (qq + 1) : rr * (qq + 1) + (xcd - rr) * qq) + lin;
  const int bx = wg % gx, t2 = wg / gx, by = t2 % gy, bz = t2 / gy;
  const int m0 = by * 256, n0 = bx * 256;

  const u16* Abase = A + (size_t)m0 * K + (size_t)bz * KC;
  const u16* Bbase = B + (size_t)n0 * K + (size_t)bz * KC;

  // staging: 4 loads/thread/operand/tile; load i covers LDS 16B slot i*512+tid.
  // linear dest (row = idx>>3, c16 = idx&7) <- global col16 (c16 ^ (row&7)).
  const u16* ap[4]; const u16* bp[4];
  #pragma unroll
  for (int i = 0; i < 4; i++) {
    int idx = i * 512 + tid;
    int row = idx >> 3;
    int col = ((idx & 7) ^ (row & 7)) * 8;
    ap[i] = Abase + (size_t)row * K + col;
    bp[i] = Bbase + (size_t)row * K + col;
  }

  f32x4 acc[8][4];
  #pragma unroll
  for (int i = 0; i < 8; i++)
    #pragma unroll
    for (int j = 0; j < 4; j++) acc[i][j] = (f32x4){0.f, 0.f, 0.f, 0.f};

  auto stA = [&](int buf, int kt) {
    #pragma unroll
    for (int i = 0; i < 4; i++)
      gl_lds16(ap[i] + (kt << 6), &As[buf][(i * 512 + wave * 64) * 8]);
  };
  auto stB = [&](int buf, int kt) {
    #pragma unroll
    for (int i = 0; i < 4; i++)
      gl_lds16(bp[i] + (kt << 6), &Bs[buf][(i * 512 + wave * 64) * 8]);
  };

  bf16x8 afr[4][2], bfr[2][2];
  auto ldA = [&](int cur, int mh) {
    #pragma unroll
    for (int f = 0; f < 4; f++) {
      int row = wm * 128 + mh * 64 + f * 16 + l16;
      int rx = row & 7;
      #pragma unroll
      for (int kk = 0; kk < 2; kk++)
        afr[f][kk] = *(const bf16x8*)&As[cur][row * 64 + (((kk * 4 + quad) ^ rx) << 3)];
    }
  };
  auto ldB = [&](int cur, int nh) {
    #pragma unroll
    for (int f = 0; f < 2; f++) {
      int row = wn * 64 + nh * 32 + f * 16 + l16;
      int rx = row & 7;
      #pragma unroll
      for (int kk = 0; kk < 2; kk++)
        bfr[f][kk] = *(const bf16x8*)&Bs[cur][row * 64 + (((kk * 4 + quad) ^ rx) << 3)];
    }
  };
  auto mmaQ = [&](int mh, int nh) {
    __builtin_amdgcn_s_setprio(1);
    #pragma unroll
    for (int kk = 0; kk < 2; kk++)
      #pragma unroll
      for (int f = 0; f < 4; f++)
        #pragma unroll
        for (int g = 0; g < 2; g++)
          acc[mh * 4 + f][nh * 2 + g] = __builtin_amdgcn_mfma_f32_16x16x32_bf16(
              afr[f][kk], bfr[g][kk], acc[mh * 4 + f][nh * 2 + g], 0, 0, 0);
    __builtin_amdgcn_s_setprio(0);
  };

  const int nk = KC >> 6;   // nk >= 24 for all launches here
  // prologue: stage tiles 0 and 1; wait only for tile 0 (vmcnt(8))
  stA(0, 0); stB(0, 0);
  if (nk > 1) {
    stA(1, 1); stB(1, 1);
    WAIT_VM(8);
  } else {
    WAIT_VM(0);
  }
  __builtin_amdgcn_s_barrier();

  for (int kt = 0; kt < nk; kt++) {
    const int cur = kt & 1;
    const bool st2 = (kt + 2 < nk);
    // phase 0: quadrant (0,0)
    ldA(cur, 0); ldB(cur, 0);
    __builtin_amdgcn_s_barrier();
    mmaQ(0, 0);
    __builtin_amdgcn_s_barrier();
    // phase 1: quadrant (0,1)
    ldB(cur, 1);
    __builtin_amdgcn_s_barrier();
    mmaQ(0, 1);
    __builtin_amdgcn_s_barrier();
    // phase 2: quadrant (1,1) — last A read of cur; then stage A(kt+2) -> cur
    ldA(cur, 1);
    WAIT_LGKM0;
    __builtin_amdgcn_s_barrier();
    if (st2) stA(cur, kt + 2);
    mmaQ(1, 1);
    __builtin_amdgcn_s_barrier();
    // phase 3: quadrant (1,0) — last B read of cur; then stage B(kt+2) -> cur
    ldB(cur, 0);
    WAIT_LGKM0;
    __builtin_amdgcn_s_barrier();
    if (st2) stB(cur, kt + 2);
    mmaQ(1, 0);
    if (kt + 1 < nk) {
      if (st2) { WAIT_VM(8); } else { WAIT_VM(0); }
    }
    __builtin_amdgcn_s_barrier();
  }

  void* Cuse;
  if constexpr (EP == 4)
    Cuse = bz == 0 ? pq.p0 : (bz == 1 ? pq.p1 : (bz == 2 ? pq.p2 : pq.p3));
  else
    Cuse = pq.p0;
  #pragma unroll
  for (int mi = 0; mi < 8; mi++)
    #pragma unroll
    for (int ni = 0; ni < 4; ni++) {
      int col = n0 + wn * 64 + ni * 16 + l16;
      #pragma unroll
      for (int r = 0; r < 4; r++)
        gemm_epilogue<EP>(acc[mi][ni][r], m0 + wm * 128 + mi * 16 + quad * 4 + r, col,
                          N, Cuse, bias, sxp, sumqp, swp, zpp, nullptr, nullptr);
    }
}

// ---- 64x128 BK=64 GEMM (N=1536 projections), counted-vmcnt 2-phase ----
// Per tile: read all 12 frags -> lgkm0 -> barrier -> stage(cur,kt+2) ->
// 16 MFMA -> vmcnt(6) -> barrier. Tile kt+1 stays resident in the other
// buffer; kt+2's 6 loads stay in flight across the barrier.
template<int EP>
__global__ __launch_bounds__(256) void gemm64_bt_kernel(
    const u16* __restrict__ A, const u16* __restrict__ B,
    void* __restrict__ Cout, void* __restrict__ Cout2, int N, int K, int KC,
    const float* __restrict__ bias,
    const float* __restrict__ sxp, const float* __restrict__ sumqp,
    const float* __restrict__ swp, const float* __restrict__ zpp,
    const float* __restrict__ gp, const float* __restrict__ residp) {
  __shared__ __align__(16) u16 As[2][64 * 64];
  __shared__ __align__(16) u16 Bs[2][128 * 64];
  const int tid = threadIdx.x;
  const int wave = tid >> 6, lane = tid & 63;
  const int wm = wave >> 1, wn = wave & 1;
  const int quad = lane >> 4, l16 = lane & 15;
  const int m0 = blockIdx.y * 64, n0 = blockIdx.x * 128;
  const int kstart = blockIdx.z * KC;

  int arow[2], acol[2], brow[4], bcol[4];
  #pragma unroll
  for (int i = 0; i < 2; i++) {
    int row = (wave * 2 + i) * 8 + (lane >> 3);
    arow[i] = row; acol[i] = (((lane & 7) - (row >> 1)) & 7) * 8;
  }
  #pragma unroll
  for (int i = 0; i < 4; i++) {
    int row = (wave * 4 + i) * 8 + (lane >> 3);
    brow[i] = row; bcol[i] = (((lane & 7) - (row >> 1)) & 7) * 8;
  }

  f32x4 acc[2][4];
  #pragma unroll
  for (int i = 0; i < 2; i++)
    #pragma unroll
    for (int j = 0; j < 4; j++) acc[i][j] = (f32x4){0.f, 0.f, 0.f, 0.f};

  const int nk = KC >> 6;
  auto stage = [&](int buf, int k0) {
    #pragma unroll
    for (int i = 0; i < 2; i++)
      gl_lds16(A + (size_t)(m0 + arow[i]) * K + kstart + k0 + acol[i],
               &As[buf][(wave * 2 + i) * 512]);
    #pragma unroll
    for (int i = 0; i < 4; i++)
      gl_lds16(B + (size_t)(n0 + brow[i]) * K + kstart + k0 + bcol[i],
               &Bs[buf][(wave * 4 + i) * 512]);
  };
  stage(0, 0);
  if (nk > 1) {
    stage(1, 64);
    WAIT_VM(6);
  } else {
    WAIT_VM(0);
  }
  __builtin_amdgcn_s_barrier();

  for (int kt = 0; kt < nk; kt++) {
    const int cur = kt & 1;
    const bool st2 = (kt + 2 < nk);
    bf16x8 af[2][2], bfv[2][4];
    #pragma unroll
    for (int s = 0; s < 2; s++) {
      #pragma unroll
      for (int mi = 0; mi < 2; mi++) {
        int row = wm * 32 + mi * 16 + l16;
        int slot = ((s * 4 + quad) + (row >> 1)) & 7;
        af[s][mi] = *(const bf16x8*)&As[cur][row * 64 + slot * 8];
      }
      #pragma unroll
      for (int ni = 0; ni < 4; ni++) {
        int row = wn * 64 + ni * 16 + l16;
        int slot = ((s * 4 + quad) + (row >> 1)) & 7;
        bfv[s][ni] = *(const bf16x8*)&Bs[cur][row * 64 + slot * 8];
      }
    }
    WAIT_LGKM0;
    __builtin_amdgcn_s_barrier();
    if (st2) stage(cur, (kt + 2) << 6);
    __builtin_amdgcn_s_setprio(1);
    #pragma unroll
    for (int s = 0; s < 2; s++)
      #pragma unroll
      for (int mi = 0; mi < 2; mi++)
        #pragma unroll
        for (int ni = 0; ni < 4; ni++)
          acc[mi][ni] = __builtin_amdgcn_mfma_f32_16x16x32_bf16(af[s][mi], bfv[s][ni], acc[mi][ni], 0, 0, 0);
    __builtin_amdgcn_s_setprio(0);
    if (kt + 1 < nk) {
      if (st2) { WAIT_VM(6); } else { WAIT_VM(0); }
    }
    __builtin_amdgcn_s_barrier();
  }
  void* Cuse = (EP == 4 && blockIdx.z) ? Cout2 : Cout;
  #pragma unroll
  for (int mi = 0; mi < 2; mi++)
    #pragma unroll
    for (int ni = 0; ni < 4; ni++) {
      int col = n0 + wn * 64 + ni * 16 + l16;
      #pragma unroll
      for (int r = 0; r < 4; r++)
        gemm_epilogue<EP>(acc[mi][ni][r], m0 + wm * 32 + mi * 16 + quad * 4 + r, col,
                          N, Cuse, bias, sxp, sumqp, swp, zpp, gp, residp);
    }
}

// split-K tail: out = (P0+P1+P2+P3+bias)*g + resid (fp32)
__global__ __launch_bounds__(256) void splitk_reduce4_kernel(
    const float* __restrict__ P0, const float* __restrict__ P1,
    const float* __restrict__ P2, const float* __restrict__ P3,
    float* __restrict__ out, const float* __restrict__ bias,
    const float* __restrict__ g, const float* __restrict__ resid,
    int N, int n4) {
  int stride = gridDim.x * 256;
  for (int i = blockIdx.x * 256 + threadIdx.x; i < n4; i += stride) {
    float4 a = ((const float4*)P0)[i];
    float4 b = ((const float4*)P1)[i];
    float4 c = ((const float4*)P2)[i];
    float4 d = ((const float4*)P3)[i];
    float4 r = ((const float4*)resid)[i];
    int col = (i * 4) % N;
    float4 o;
    o.x = (a.x + b.x + c.x + d.x + bias[col]) * g[col] + r.x;
    o.y = (a.y + b.y + c.y + d.y + bias[col + 1]) * g[col + 1] + r.y;
    o.z = (a.z + b.z + c.z + d.z + bias[col + 2]) * g[col + 2] + r.z;
    o.w = (a.w + b.w + c.w + d.w + bias[col + 3]) * g[col + 3] + r.w;
    ((float4*)out)[i] = o;
  }
}

// RMS+gate+RoPE for q,k sections + plain convert for v; fp32 qkv -> bf16 qkvb.
__global__ __launch_bounds__(256) void rmsrope_b_kernel(
    const float* __restrict__ qkv, u16* __restrict__ qkvb,
    const float* __restrict__ gq, const float* __restrict__ gk,
    const float* __restrict__ freqs, const int* __restrict__ gsz) {
  __shared__ float scr[4];
  const int row = blockIdx.x, tid = threadIdx.x;
  const float* base = qkv + (size_t)row * 4608;
  u16* ob = qkvb + (size_t)row * 4608;
  const int gh = gsz[1], gw = gsz[2];
  const int hw = gh * gw;
  const int fi = row / hw, rem = row - fi * hw;
  const int hi = rem / gw, wi = rem - hi * gw;
  #pragma unroll
  for (int part = 0; part < 2; part++) {
    const float* p = base + part * 1536;
    u16* o = ob + part * 1536;
    const float* g = part ? gk : gq;
    const float sc = part ? 1.f : 0.08838834764831845f;
    float v[6], s2 = 0.f;
    #pragma unroll
    for (int t = 0; t < 6; t++) { v[t] = p[tid + t * 256]; s2 += v[t] * v[t]; }
    s2 = bred_sum(s2, scr);
    float inv = rsqrtf(s2 / 1536.f + 1e-6f);
    #pragma unroll
    for (int t = 0; t < 3; t++) {
      int pr = tid + t * 256;
      int c = pr & 63;
      int frow = (c < 22) ? fi : (c < 43 ? hi : wi);
      const float* fr = freqs + ((size_t)frow * 64 + c) * 2;
      float cv = fr[0], sv = fr[1];
      float x0 = p[2 * pr] * inv * g[2 * pr];
      float x1 = p[2 * pr + 1] * inv * g[2 * pr + 1];
      o[2 * pr] = f2b((x0 * cv - x1 * sv) * sc);
      o[2 * pr + 1] = f2b((x0 * sv + x1 * cv) * sc);
    }
  }
  #pragma unroll
  for (int t = 0; t < 6; t++) {
    int i = tid + t * 256;
    ob[3072 + i] = f2b(base[3072 + i]);
  }
}

// RMS (optional) + scale, fp32 -> bf16
__global__ __launch_bounds__(256) void rms_bf16_kernel(
    const float* __restrict__ X, u16* __restrict__ O, const float* __restrict__ g,
    int ldi, int ldo, float scale) {
  __shared__ float scr[4];
  const int row = blockIdx.x, tid = threadIdx.x;
  const float* xr = X + (size_t)row * ldi;
  u16* orow = O + (size_t)row * ldo;
  float v[6], s2 = 0.f;
  #pragma unroll
  for (int t = 0; t < 6; t++) { v[t] = xr[tid + t * 256]; s2 += v[t] * v[t]; }
  s2 = bred_sum(s2, scr);
  float inv = rsqrtf(s2 / 1536.f + 1e-6f) * scale;
  #pragma unroll
  for (int t = 0; t < 6; t++) {
    int i = tid + t * 256;
    orow[i] = f2b(v[t] * inv * g[i]);
  }
}

// V transpose: fp32 V[kv][ld] (per-head 128 cols) -> bf16 Vt[head][hd][Skv]
__global__ __launch_bounds__(256) void vtrans_kernel(
    const float* __restrict__ V, int ld, u16* __restrict__ Vt, int Skv) {
  __shared__ u16 T[64 * 136];
  const int h = blockIdx.y, k0 = blockIdx.x * 64, tid = threadIdx.x;
  #pragma unroll
  for (int i = 0; i < 8; i++) {
    int f4 = i * 256 + tid;
    int row = f4 >> 5, c4 = f4 & 31;
    float4 v = *(const float4*)(V + (size_t)(k0 + row) * ld + h * 128 + c4 * 4);
    ushort4 b;
    b.x = f2b(v.x); b.y = f2b(v.y); b.z = f2b(v.z); b.w = f2b(v.w);
    *(ushort4*)&T[row * 136 + c4 * 4] = b;
  }
  __syncthreads();
  #pragma unroll
  for (int i = 0; i < 4; i++) {
    int f8 = i * 256 + tid;
    int hd = f8 >> 3, kc = f8 & 7;
    u16 tmp[8];
    #pragma unroll
    for (int j = 0; j < 8; j++) tmp[j] = T[(kc * 8 + j) * 136 + hd];
    *(uint4*)(Vt + ((size_t)h * 128 + hd) * Skv + k0 + kc * 8) = *(const uint4*)tmp;
  }
}

// ---- MFMA flash attention ----
__global__ __launch_bounds__(256) void fattn_kernel(
    const u16* __restrict__ Q, int ldq, const u16* __restrict__ Kg, int ldk,
    const u16* __restrict__ Vtg, u16* __restrict__ O, int ldo,
    const int* __restrict__ klen_ptr, int kmax) {
  __shared__ __align__(16) u16 Qs[64 * 136];
  __shared__ __align__(16) u16 Ks[64 * 136];
  __shared__ __align__(16) u16 Vt[128 * 72];
  __shared__ __align__(16) u16 Pt[4][16 * 72];
  const int tid = threadIdx.x, wave = tid >> 6, lane = tid & 63;
  const int quad = lane >> 4, l16 = lane & 15;
  const int h = blockIdx.y;
  const int q0 = blockIdx.x * 64;
  int klen = klen_ptr[0]; if (klen > kmax) klen = kmax;
  const u16* vbase = Vtg + (size_t)h * 128 * kmax;

  #pragma unroll
  for (int i = 0; i < 4; i++) {
    int c8 = i * 256 + tid;
    int row = c8 >> 4, cc = (c8 & 15) * 8;
    *(uint4*)&Qs[row * 136 + cc] = *(const uint4*)(Q + (size_t)(q0 + row) * ldq + h * 128 + cc);
  }
  __syncthreads();
  bf16x8 qf[4];
  #pragma unroll
  for (int s = 0; s < 4; s++)
    qf[s] = *(const bf16x8*)&Qs[(wave * 16 + l16) * 136 + s * 32 + quad * 8];

  float m_r[4] = {-1e30f, -1e30f, -1e30f, -1e30f};
  float l_r[4] = {0.f, 0.f, 0.f, 0.f};
  f32x4 oacc[8];
  #pragma unroll
  for (int n8 = 0; n8 < 8; n8++) oacc[n8] = (f32x4){0.f, 0.f, 0.f, 0.f};

  const int ktiles = (klen + 63) >> 6;
  for (int kt = 0; kt < ktiles; kt++) {
    const int k0 = kt * 64;
    __syncthreads();
    #pragma unroll
    for (int i = 0; i < 4; i++) {
      int c8 = i * 256 + tid;
      int row = c8 >> 4, cc = (c8 & 15) * 8;
      *(uint4*)&Ks[row * 136 + cc] = *(const uint4*)(Kg + (size_t)(k0 + row) * ldk + h * 128 + cc);
    }
    #pragma unroll
    for (int i = 0; i < 4; i++) {
      int f8 = i * 256 + tid;
      int hd = f8 >> 3, kc = f8 & 7;
      *(uint4*)&Vt[hd * 72 + kc * 8] = *(const uint4*)(vbase + (size_t)hd * kmax + k0 + kc * 8);
    }
    __syncthreads();
    f32x4 sacc[4];
    #pragma unroll
    for (int ni = 0; ni < 4; ni++) sacc[ni] = (f32x4){0.f, 0.f, 0.f, 0.f};
    #pragma unroll
    for (int ni = 0; ni < 4; ni++)
      #pragma unroll
      for (int s = 0; s < 4; s++) {
        bf16x8 kf = *(const bf16x8*)&Ks[(ni * 16 + l16) * 136 + s * 32 + quad * 8];
        sacc[ni] = __builtin_amdgcn_mfma_f32_16x16x32_bf16(qf[s], kf, sacc[ni], 0, 0, 0);
      }
    float alpha_r[4];
    #pragma unroll
    for (int r = 0; r < 4; r++) {
      float mx = -1e30f;
      #pragma unroll
      for (int ni = 0; ni < 4; ni++) {
        int col = k0 + ni * 16 + l16;
        float sv = (col < klen) ? sacc[ni][r] : -1e30f;
        sacc[ni][r] = sv;
        mx = fmaxf(mx, sv);
      }
      #pragma unroll
      for (int off = 1; off < 16; off <<= 1) mx = fmaxf(mx, __shfl_xor(mx, off, 64));
      float mnew = fmaxf(m_r[r], mx);
      float alpha = __expf(m_r[r] - mnew);
      float rsum = 0.f;
      float pv[4];
      #pragma unroll
      for (int ni = 0; ni < 4; ni++) {
        float p = __expf(sacc[ni][r] - mnew);
        pv[ni] = p;
        rsum += p;
      }
      #pragma unroll
      for (int off = 1; off < 16; off <<= 1) rsum += __shfl_xor(rsum, off, 64);
      l_r[r] = l_r[r] * alpha + rsum;
      m_r[r] = mnew;
      alpha_r[r] = alpha;
      #pragma unroll
      for (int ni = 0; ni < 4; ni++)
        Pt[wave][(quad * 4 + r) * 72 + ni * 16 + l16] = f2b(pv[ni]);
    }
    #pragma unroll
    for (int n8 = 0; n8 < 8; n8++)
      #pragma unroll
      for (int r = 0; r < 4; r++) oacc[n8][r] *= alpha_r[r];
    #pragma unroll
    for (int s2 = 0; s2 < 2; s2++) {
      bf16x8 pf = *(const bf16x8*)&Pt[wave][l16 * 72 + s2 * 32 + quad * 8];
      #pragma unroll
      for (int n8 = 0; n8 < 8; n8++) {
        bf16x8 vf = *(const bf16x8*)&Vt[(n8 * 16 + l16) * 72 + s2 * 32 + quad * 8];
        oacc[n8] = __builtin_amdgcn_mfma_f32_16x16x32_bf16(pf, vf, oacc[n8], 0, 0, 0);
      }
    }
  }
  float rl[4];
  #pragma unroll
  for (int r = 0; r < 4; r++) rl[r] = 1.f / l_r[r];
  #pragma unroll
  for (int n8 = 0; n8 < 8; n8++)
    #pragma unroll
    for (int r = 0; r < 4; r++) {
      int row = q0 + wave * 16 + quad * 4 + r;
      O[(size_t)row * ldo + h * 128 + n8 * 16 + l16] = f2b(oacc[n8][r] * rl[r]);
    }
}

// out_bf16 = LN(x) * (addone + w) + b
__global__ __launch_bounds__(256) void ln_affine_kernel(
    const float* __restrict__ X, u16* __restrict__ O,
    const float* __restrict__ w, const float* __restrict__ b, float addone) {
  __shared__ float scr[4];
  const int row = blockIdx.x, tid = threadIdx.x;
  const float* xr = X + (size_t)row * 1536;
  float v[6], s = 0.f, s2 = 0.f;
  #pragma unroll
  for (int t = 0; t < 6; t++) { v[t] = xr[tid + t * 256]; s += v[t]; s2 += v[t] * v[t]; }
  s = bred_sum(s, scr); s2 = bred_sum(s2, scr);
  float mean = s / 1536.f;
  float inv = rsqrtf(s2 / 1536.f - mean * mean + 1e-6f);
  #pragma unroll
  for (int t = 0; t < 6; t++) {
    int i = tid + t * 256;
    O[(size_t)row * 1536 + i] = f2b((v[t] - mean) * inv * (addone + w[i]) + b[i]);
  }
}

extern "C" void kernel_launch(void* const* d_in, const int* in_sizes, int n_in,
                              void* d_out, int out_size, void* d_ws, size_t ws_size,
                              hipStream_t stream) {
  (void)in_sizes; (void)n_in; (void)out_size; (void)ws_size;
  const int S = 2560, D = 1536, L2C = 512, FF = 8960, ND = 4608, CKV = 3072;

  const float* x = (const float*)d_in[0];
  const float* e = (const float*)d_in[1];
  const int* seq_lens = (const int*)d_in[2];
  const int* grid_sz = (const int*)d_in[3];
  const float* freqs = (const float*)d_in[4];
  const float* context = (const float*)d_in[5];
  const int* ctx_lens = (const int*)d_in[6];
  const float* modulation = (const float*)d_in[7];
  const float* wq = (const float*)d_in[8];  const float* bq = (const float*)d_in[9];
  const float* wk = (const float*)d_in[10]; const float* bk = (const float*)d_in[11];
  const float* wv = (const float*)d_in[12]; const float* bv = (const float*)d_in[13];
  const float* wo = (const float*)d_in[14]; const float* bo = (const float*)d_in[15];
  const float* gq = (const float*)d_in[16]; const float* gk = (const float*)d_in[17];
  const float* n3w = (const float*)d_in[18]; const float* n3b = (const float*)d_in[19];
  const float* cwq = (const float*)d_in[20]; const float* cbq = (const float*)d_in[21];
  const float* cwk = (const float*)d_in[22]; const float* cbk = (const float*)d_in[23];
  const float* cwv = (const float*)d_in[24]; const float* cbv = (const float*)d_in[25];
  const float* cwo = (const float*)d_in[26]; const float* cbo = (const float*)d_in[27];
  const float* cgq = (const float*)d_in[28]; const float* cgk = (const float*)d_in[29];
  const float* w1 = (const float*)d_in[30]; const float* b1 = (const float*)d_in[31];
  const float* w2 = (const float*)d_in[32]; const float* b2 = (const float*)d_in[33];

  char* wsb = (char*)d_ws;
  size_t off = 0;
  auto alloc = [&](size_t bytes) -> void* {
    void* r = wsb + off;
    off += (bytes + 255) & ~(size_t)255;
    return r;
  };
  float* em   = (float*)alloc((size_t)6 * D * 4);
  float* bckv = (float*)alloc((size_t)CKV * 4);
  float* ball = (float*)alloc((size_t)ND * 4);
  float* sx   = (float*)alloc((size_t)S * 4);
  float* sumq = (float*)alloc((size_t)S * 4);
  float* sw   = (float*)alloc((size_t)ND * 4);
  float* zp   = (float*)alloc((size_t)ND * 4);
  u16* qx     = (u16*)alloc((size_t)S * D * 2);      // union: cvtg; P0 head
  u16* qw     = (u16*)alloc((size_t)ND * D * 2);     // union: vtg; P0 tail (qx+qw = 22.0MB >= 15.7MB)
  float* qkv  = (float*)alloc((size_t)S * ND * 4);   // union: h3
  u16* qkvb   = (u16*)alloc((size_t)S * ND * 2);     // union: P1 (23.6MB >= 15.7MB)
  u16* attnb  = (u16*)alloc((size_t)S * D * 2);      // union: h2; P2 head
  u16* hx     = (u16*)alloc((size_t)S * D * 2);      // union: cqb; P2 tail (attnb+hx = 15.73MB)
  float* cq   = (float*)alloc((size_t)S * D * 4);    // union: x2
  float* ckv  = (float*)alloc((size_t)L2C * CKV * 4);
  u16* ctxb   = (u16*)alloc((size_t)L2C * D * 2);    // union: ckvb
  u16* cattn  = (u16*)alloc((size_t)S * D * 2);      // P3 head
  u16* wo_b   = (u16*)alloc((size_t)D * D * 2);      // P3 mid
  u16* cwq_b  = (u16*)alloc((size_t)D * D * 2);      // P3 tail (cattn+wo_b+cwq_b = 17.3MB)
  u16* cwkv_b = (u16*)alloc((size_t)2 * D * D * 2);
  u16* cwo_b  = (u16*)alloc((size_t)D * D * 2);
  u16* w1_b   = (u16*)alloc((size_t)FF * D * 2);
  u16* w2_b   = (u16*)alloc((size_t)D * FF * 2);
  u16* h3 = (u16*)qkv;
  u16* h2 = attnb;
  u16* vtg = qw;        // [12][128][2560] bf16
  u16* cvtg = qx;       // [12][128][512] bf16
  u16* cqb = hx;
  u16* ckvb = ctxb;
  float* x2 = cq;
  float* x1 = (float*)d_out;
  float* outp = (float*)d_out;
  // split-K=4 partials (all regions dead during FFN/w2):
  float* P0 = (float*)qx;     // qx+qw region
  float* P1 = (float*)qkvb;   // qkvb region
  float* P2 = (float*)attnb;  // attnb+hx region (contiguous, 15.73MB)
  float* P3 = (float*)cattn;  // cattn+wo_b+cwq_b region (contiguous, 17.3MB)

  auto cvt = [&](const float* in, u16* op, size_t n) {
    int n4 = (int)(n / 4);
    int blocks = (n4 + 255) / 256; if (blocks > 4096) blocks = 4096;
    cvt_bf16_kernel<<<blocks, 256, 0, stream>>>(in, op, n4);
  };

  pack_kernel<<<36, 256, 0, stream>>>(e, modulation, cbk, cbv, em, bckv);
  cvt(wo, wo_b, (size_t)D * D);
  cvt(cwq, cwq_b, (size_t)D * D);
  cvt(cwk, cwkv_b, (size_t)D * D);
  cvt(cwv, cwkv_b + (size_t)D * D, (size_t)D * D);
  cvt(cwo, cwo_b, (size_t)D * D);
  cvt(w1, w1_b, (size_t)FF * D);
  cvt(w2, w2_b, (size_t)D * FF);
  cvt(context, ctxb, (size_t)L2C * D);

  ln_quant_kernel<<<S, 256, 0, stream>>>(x, em, qx, sx, sumq);
  quantw_kernel<<<ND, 256, 0, stream>>>(wq, wk, wv, bq, bk, bv, qw, sw, zp, ball);

  // qkv = dequant(qx @ qw^T) : [S][4608] fp32   (180 blocks @256x256)
  {
    PtrQuad pq{qkv, nullptr, nullptr, nullptr};
    gemm256_bt_kernel<1><<<dim3(ND / 256, S / 256), 512, 0, stream>>>(
        qx, qw, pq, ND, D, D, ball, sx, sumq, sw, zp);
  }

  rmsrope_b_kernel<<<S, 256, 0, stream>>>(qkv, qkvb, gq, gk, freqs, grid_sz);
  vtrans_kernel<<<dim3(S / 64, 12), 256, 0, stream>>>(qkv + 3072, ND, vtg, S);

  fattn_kernel<<<dim3(S / 64, 12), 256, 0, stream>>>(
      qkvb, ND, qkvb + 1536, ND, vtg, attnb, D, seq_lens, S);

  // x1 = x + (attn @ wo^T + bo) * gm
  gemm64_bt_kernel<2><<<dim3(D / 128, S / 64), 256, 0, stream>>>(
      attnb, wo_b, x1, nullptr, D, D, D, bo, nullptr, nullptr, nullptr, nullptr, em + 2 * D, x);

  ln_affine_kernel<<<S, 256, 0, stream>>>(x1, hx, n3w, n3b, 0.f);

  gemm64_bt_kernel<0><<<dim3(D / 128, S / 64), 256, 0, stream>>>(
      hx, cwq_b, cq, nullptr, D, D, D, cbq, nullptr, nullptr, nullptr, nullptr, nullptr, nullptr);
  gemm64_bt_kernel<0><<<dim3(CKV / 128, L2C / 64), 256, 0, stream>>>(
      ctxb, cwkv_b, ckv, nullptr, CKV, D, D, bckv, nullptr, nullptr, nullptr, nullptr, nullptr, nullptr);

  rms_bf16_kernel<<<S, 256, 0, stream>>>(cq, cqb, cgq, D, D, 0.08838834764831845f);
  rms_bf16_kernel<<<L2C, 256, 0, stream>>>(ckv, ckvb, cgk, CKV, D, 1.f);
  vtrans_kernel<<<dim3(L2C / 64, 12), 256, 0, stream>>>(ckv + 1536, CKV, cvtg, L2C);

  fattn_kernel<<<dim3(S / 64, 12), 256, 0, stream>>>(
      cqb, D, ckvb, D, cvtg, cattn, D, ctx_lens, L2C);

  // x2 = x1 + cattn @ cwo^T + cbo
  gemm64_bt_kernel<2><<<dim3(D / 128, S / 64), 256, 0, stream>>>(
      cattn, cwo_b, x2, nullptr, D, D, D, cbo, nullptr, nullptr, nullptr, nullptr, nullptr, x1);

  ln_affine_kernel<<<S, 256, 0, stream>>>(x2, h2, em + 4 * D, em + 3 * D, 1.f);

  // h3 = gelu(h2 @ w1^T + b1) (bf16)   (350 blocks @256x256)
  {
    PtrQuad pq{h3, nullptr, nullptr, nullptr};
    gemm256_bt_kernel<3><<<dim3(FF / 256, S / 256), 512, 0, stream>>>(
        h2, w1_b, pq, FF, D, D, b1, nullptr, nullptr, nullptr, nullptr);
  }

  // w2 split-K=4: raw partials P0..P3 (240 blocks @256x256), then fused reduce
  {
    PtrQuad pq{P0, P1, P2, P3};
    gemm256_bt_kernel<4><<<dim3(D / 256, S / 256, 4), 512, 0, stream>>>(
        h3, w2_b, pq, D, FF, FF / 4, nullptr, nullptr, nullptr, nullptr, nullptr);
  }
  splitk_reduce4_kernel<<<960, 256, 0, stream>>>(
      P0, P1, P2, P3, outp, b2, em + 5 * D, x2, D, S * D / 4);
}